// Round 1
// baseline (213.650 us; speedup 1.0000x reference)
//
#include <hip/hip_runtime.h>
#include <math.h>

#define BATCH 524288
#define NJ 12

// ws float layout: joint j at [j*20 .. j*20+18]:
//   0:wn 1-3:u 4-6:ru 7-9:Kru 10-12:K2ru 13-18: uu00,uu01,uu02,uu11,uu12,uu22
// T0 at [240..251]: R0 row-major (9), p0 (3)

__global__ void precompute_kernel(const float* __restrict__ twist,
                                  const float* __restrict__ init_p,
                                  const float* __restrict__ init_rpy,
                                  float* __restrict__ ws) {
    int j = threadIdx.x;
    if (j < NJ) {
        float rho0 = twist[j*6+0], rho1 = twist[j*6+1], rho2 = twist[j*6+2];
        float w0   = twist[j*6+3], w1   = twist[j*6+4], w2   = twist[j*6+5];
        float wn = sqrtf(w0*w0 + w1*w1 + w2*w2 + 1e-12f);
        float inv = 1.0f / wn;
        float u0 = w0*inv, u1 = w1*inv, u2 = w2*inv;
        float ru0 = rho0*inv, ru1 = rho1*inv, ru2 = rho2*inv;
        // Kru = u x ru
        float kru0 = u1*ru2 - u2*ru1;
        float kru1 = u2*ru0 - u0*ru2;
        float kru2 = u0*ru1 - u1*ru0;
        // K2ru = u (u . ru) - ru   (since |u| = 1)
        float ud = u0*ru0 + u1*ru1 + u2*ru2;
        float k2ru0 = u0*ud - ru0;
        float k2ru1 = u1*ud - ru1;
        float k2ru2 = u2*ud - ru2;
        float* o = ws + j*20;
        o[0] = wn;  o[1] = u0;  o[2] = u1;  o[3] = u2;
        o[4] = ru0; o[5] = ru1; o[6] = ru2;
        o[7] = kru0; o[8] = kru1; o[9] = kru2;
        o[10] = k2ru0; o[11] = k2ru1; o[12] = k2ru2;
        o[13] = u0*u0; o[14] = u0*u1; o[15] = u0*u2;
        o[16] = u1*u1; o[17] = u1*u2; o[18] = u2*u2;
    } else if (j == NJ) {
        float r = init_rpy[0], p = init_rpy[1], y = init_rpy[2];
        float cr = cosf(r), sr = sinf(r);
        float cp = cosf(p), sp = sinf(p);
        float cy = cosf(y), sy = sinf(y);
        float* o = ws + NJ*20;
        o[0] = cy*cp; o[1] = cy*sp*sr - sy*cr; o[2] = cy*sp*cr + sy*sr;
        o[3] = sy*cp; o[4] = sy*sp*sr + cy*cr; o[5] = sy*sp*cr - cy*sr;
        o[6] = -sp;   o[7] = cp*sr;            o[8] = cp*cr;
        o[9] = init_p[0]; o[10] = init_p[1]; o[11] = init_p[2];
    }
}

template<int IN, int OUT>
__device__ __forceinline__ void dense_relu(const float* __restrict__ W,
                                           const float* __restrict__ b,
                                           const float* in, float* out) {
#pragma unroll
    for (int o = 0; o < OUT; o++) {
        float a = b[o];
#pragma unroll
        for (int i = 0; i < IN; i++) a = fmaf(W[o*IN + i], in[i], a);
        out[o] = fmaxf(a, 0.0f);
    }
}

__global__ __launch_bounds__(256) void fk_kernel(
    const float* __restrict__ mc,
    const float* __restrict__ W1, const float* __restrict__ b1,
    const float* __restrict__ W2, const float* __restrict__ b2,
    const float* __restrict__ W3, const float* __restrict__ b3,
    const float* __restrict__ W4, const float* __restrict__ b4,
    const float* __restrict__ W5, const float* __restrict__ b5,
    const float* __restrict__ jc,
    float* __restrict__ out) {
    int e = blockIdx.x * blockDim.x + threadIdx.x;

    float4 x4 = ((const float4*)mc)[e];
    float x[4] = {x4.x, x4.y, x4.z, x4.w};

    float h1[16], h2[32], h3[64], h4[32], q[12];
    dense_relu<4, 16>(W1, b1, x,  h1);
    dense_relu<16, 32>(W2, b2, h1, h2);
    dense_relu<32, 64>(W3, b3, h2, h3);
    dense_relu<64, 32>(W4, b4, h3, h4);
    dense_relu<32, 12>(W5, b5, h4, q);

    // FK chain: carry = [M | v] (bottom row implicit 0001), init identity
    float M00 = 1.f, M01 = 0.f, M02 = 0.f;
    float M10 = 0.f, M11 = 1.f, M12 = 0.f;
    float M20 = 0.f, M21 = 0.f, M22 = 1.f;
    float v0 = 0.f, v1 = 0.f, v2 = 0.f;

#pragma unroll
    for (int j = 0; j < NJ; j++) {
        const float* c = jc + j*20;
        float wn = c[0];
        float u0 = c[1], u1 = c[2], u2 = c[3];
        float ru0 = c[4], ru1 = c[5], ru2 = c[6];
        float kru0 = c[7], kru1 = c[8], kru2 = c[9];
        float k2ru0 = c[10], k2ru1 = c[11], k2ru2 = c[12];
        float uu00 = c[13], uu01 = c[14], uu02 = c[15];
        float uu11 = c[16], uu12 = c[17], uu22 = c[18];

        float th = q[j] * wn;
        float s = __sinf(th);
        float cth = __cosf(th);
        float cc = 1.0f - cth;
        float t = th - s;

        float R00 = 1.0f + cc*(uu00 - 1.0f);
        float R01 = cc*uu01 - s*u2;
        float R02 = cc*uu02 + s*u1;
        float R10 = cc*uu01 + s*u2;
        float R11 = 1.0f + cc*(uu11 - 1.0f);
        float R12 = cc*uu12 - s*u0;
        float R20 = cc*uu02 - s*u1;
        float R21 = cc*uu12 + s*u0;
        float R22 = 1.0f + cc*(uu22 - 1.0f);

        float p0 = th*ru0 + cc*kru0 + t*k2ru0;
        float p1 = th*ru1 + cc*kru1 + t*k2ru1;
        float p2 = th*ru2 + cc*kru2 + t*k2ru2;

        // carry' = carry @ S
        float n00 = M00*R00 + M01*R10 + M02*R20;
        float n01 = M00*R01 + M01*R11 + M02*R21;
        float n02 = M00*R02 + M01*R12 + M02*R22;
        float n10 = M10*R00 + M11*R10 + M12*R20;
        float n11 = M10*R01 + M11*R11 + M12*R21;
        float n12 = M10*R02 + M11*R12 + M12*R22;
        float n20 = M20*R00 + M21*R10 + M22*R20;
        float n21 = M20*R01 + M21*R11 + M22*R21;
        float n22 = M20*R02 + M21*R12 + M22*R22;
        v0 += M00*p0 + M01*p1 + M02*p2;
        v1 += M10*p0 + M11*p1 + M12*p2;
        v2 += M20*p0 + M21*p1 + M22*p2;
        M00 = n00; M01 = n01; M02 = n02;
        M10 = n10; M11 = n11; M12 = n12;
        M20 = n20; M21 = n21; M22 = n22;
    }

    // final: out = carry @ T0
    const float* t0 = jc + NJ*20;
    float A00 = t0[0], A01 = t0[1], A02 = t0[2];
    float A10 = t0[3], A11 = t0[4], A12 = t0[5];
    float A20 = t0[6], A21 = t0[7], A22 = t0[8];
    float P0  = t0[9], P1  = t0[10], P2 = t0[11];

    float F00 = M00*A00 + M01*A10 + M02*A20;
    float F01 = M00*A01 + M01*A11 + M02*A21;
    float F02 = M00*A02 + M01*A12 + M02*A22;
    float F10 = M10*A00 + M11*A10 + M12*A20;
    float F11 = M10*A01 + M11*A11 + M12*A21;
    float F12 = M10*A02 + M11*A12 + M12*A22;
    float F20 = M20*A00 + M21*A10 + M22*A20;
    float F21 = M20*A01 + M21*A11 + M22*A21;
    float F22 = M20*A02 + M21*A12 + M22*A22;
    float Fv0 = M00*P0 + M01*P1 + M02*P2 + v0;
    float Fv1 = M10*P0 + M11*P1 + M12*P2 + v1;
    float Fv2 = M20*P0 + M21*P1 + M22*P2 + v2;

    float4* o4 = (float4*)(out + (size_t)e * 16);
    o4[0] = make_float4(F00, F01, F02, Fv0);
    o4[1] = make_float4(F10, F11, F12, Fv1);
    o4[2] = make_float4(F20, F21, F22, Fv2);
    o4[3] = make_float4(0.f, 0.f, 0.f, 1.f);
}

extern "C" void kernel_launch(void* const* d_in, const int* in_sizes, int n_in,
                              void* d_out, int out_size, void* d_ws, size_t ws_size,
                              hipStream_t stream) {
    const float* mc      = (const float*)d_in[0];
    const float* W1      = (const float*)d_in[1];
    const float* b1      = (const float*)d_in[2];
    const float* W2      = (const float*)d_in[3];
    const float* b2      = (const float*)d_in[4];
    const float* W3      = (const float*)d_in[5];
    const float* b3      = (const float*)d_in[6];
    const float* W4      = (const float*)d_in[7];
    const float* b4      = (const float*)d_in[8];
    const float* W5      = (const float*)d_in[9];
    const float* b5      = (const float*)d_in[10];
    const float* twist   = (const float*)d_in[11];
    const float* init_p  = (const float*)d_in[12];
    const float* init_rpy= (const float*)d_in[13];
    float* out = (float*)d_out;
    float* ws  = (float*)d_ws;

    precompute_kernel<<<1, 64, 0, stream>>>(twist, init_p, init_rpy, ws);
    fk_kernel<<<BATCH / 256, 256, 0, stream>>>(
        mc, W1, b1, W2, b2, W3, b3, W4, b4, W5, b5, ws, out);
}

// Round 2
// 148.659 us; speedup vs baseline: 1.4372x; 1.4372x over previous
//
#include <hip/hip_runtime.h>
#include <math.h>

#define BATCH 524288
#define NJ 12

typedef _Float16 half4 __attribute__((ext_vector_type(4)));
typedef float f32x4 __attribute__((ext_vector_type(4)));

#define MFMA16(a, b, c) __builtin_amdgcn_mfma_f32_16x16x16f16((a), (b), (c), 0, 0, 0)

__device__ __forceinline__ f32x4 ld4(const float* p) { return *(const f32x4*)p; }

// split v into f16 hi + f16 lo where lo is pre-scaled by 2^11 (avoids f16 denorms);
// true value = hi + lo * 2^-11
__device__ __forceinline__ void split4(f32x4 v, half4& h, half4& l) {
    half4 hh, ll;
#pragma unroll
    for (int i = 0; i < 4; i++) {
        float x = v[i];
        _Float16 hi = (_Float16)x;
        hh[i] = hi;
        ll[i] = (_Float16)((x - (float)hi) * 2048.0f);
    }
    h = hh; l = ll;
}

__device__ __forceinline__ f32x4 relu4(f32x4 v) {
    f32x4 r;
#pragma unroll
    for (int i = 0; i < 4; i++) r[i] = fmaxf(v[i], 0.0f);
    return r;
}

// ws float layout: joint j at [j*20 .. j*20+18]; T0 at [240..251]
__global__ void precompute_kernel(const float* __restrict__ twist,
                                  const float* __restrict__ init_p,
                                  const float* __restrict__ init_rpy,
                                  float* __restrict__ ws) {
    int j = threadIdx.x;
    if (j < NJ) {
        float rho0 = twist[j*6+0], rho1 = twist[j*6+1], rho2 = twist[j*6+2];
        float w0   = twist[j*6+3], w1   = twist[j*6+4], w2   = twist[j*6+5];
        float wn = sqrtf(w0*w0 + w1*w1 + w2*w2 + 1e-12f);
        float inv = 1.0f / wn;
        float u0 = w0*inv, u1 = w1*inv, u2 = w2*inv;
        float ru0 = rho0*inv, ru1 = rho1*inv, ru2 = rho2*inv;
        float kru0 = u1*ru2 - u2*ru1;
        float kru1 = u2*ru0 - u0*ru2;
        float kru2 = u0*ru1 - u1*ru0;
        float ud = u0*ru0 + u1*ru1 + u2*ru2;
        float k2ru0 = u0*ud - ru0;
        float k2ru1 = u1*ud - ru1;
        float k2ru2 = u2*ud - ru2;
        float* o = ws + j*20;
        o[0] = wn;  o[1] = u0;  o[2] = u1;  o[3] = u2;
        o[4] = ru0; o[5] = ru1; o[6] = ru2;
        o[7] = kru0; o[8] = kru1; o[9] = kru2;
        o[10] = k2ru0; o[11] = k2ru1; o[12] = k2ru2;
        o[13] = u0*u0; o[14] = u0*u1; o[15] = u0*u2;
        o[16] = u1*u1; o[17] = u1*u2; o[18] = u2*u2;
    } else if (j == NJ) {
        float r = init_rpy[0], p = init_rpy[1], y = init_rpy[2];
        float cr = cosf(r), sr = sinf(r);
        float cp = cosf(p), sp = sinf(p);
        float cy = cosf(y), sy = sinf(y);
        float* o = ws + NJ*20;
        o[0] = cy*cp; o[1] = cy*sp*sr - sy*cr; o[2] = cy*sp*cr + sy*sr;
        o[3] = sy*cp; o[4] = sy*sp*sr + cy*cr; o[5] = sy*sp*cr - cy*sr;
        o[6] = -sp;   o[7] = cp*sr;            o[8] = cp*cr;
        o[9] = init_p[0]; o[10] = init_p[1]; o[11] = init_p[2];
    }
}

__global__ __launch_bounds__(256) void fk_kernel(
    const float* __restrict__ mc,
    const float* __restrict__ W1, const float* __restrict__ b1,
    const float* __restrict__ W2, const float* __restrict__ b2,
    const float* __restrict__ W3, const float* __restrict__ b3,
    const float* __restrict__ W4, const float* __restrict__ b4,
    const float* __restrict__ W5, const float* __restrict__ b5,
    const float* __restrict__ jc,
    float* __restrict__ out) {
    const int tid = threadIdx.x;
    const int wv = tid >> 6, lane = tid & 63;
    const int qd = lane >> 4, l16 = lane & 15;
    const int wave_base = (blockIdx.x * 4 + wv) * 64;

    // per-wave q redistribution buffer: 64 rows x 20 floats (80 B stride, 16B aligned)
    __shared__ __align__(16) float qbuf[4][64 * 20];

    const half4 HZ = {(_Float16)0, (_Float16)0, (_Float16)0, (_Float16)0};
    const f32x4 FZ = {0.0f, 0.0f, 0.0f, 0.0f};
    const float inv2048 = 1.0f / 2048.0f;

    // ---------- A fragments (weights), split hi/lo, loaded once per wave ----------
    // mfma_f32_16x16x16f16 A layout: A[m=l16][k=4*qd+j], j=0..3 -> one float4 per frag
    half4 a1h, a1l;
    {
        f32x4 w = ld4(W1 + l16 * 4);           // in-bounds for all l16
        half4 h, l; split4(w, h, l);
        a1h = (qd == 0) ? h : HZ;              // K=4 padded to 16: only quad 0 valid
        a1l = (qd == 0) ? l : HZ;
    }
    half4 a2h[2], a2l[2];
#pragma unroll
    for (int ot = 0; ot < 2; ot++) {
        f32x4 w = ld4(W2 + (ot*16 + l16)*16 + 4*qd);
        split4(w, a2h[ot], a2l[ot]);
    }
    half4 a3h[4][2], a3l[4][2];
#pragma unroll
    for (int ot = 0; ot < 4; ot++)
#pragma unroll
        for (int kc = 0; kc < 2; kc++) {
            f32x4 w = ld4(W3 + (ot*16 + l16)*32 + kc*16 + 4*qd);
            split4(w, a3h[ot][kc], a3l[ot][kc]);
        }
    half4 a4h[2][4], a4l[2][4];
#pragma unroll
    for (int ot = 0; ot < 2; ot++)
#pragma unroll
        for (int kc = 0; kc < 4; kc++) {
            f32x4 w = ld4(W4 + (ot*16 + l16)*64 + kc*16 + 4*qd);
            split4(w, a4h[ot][kc], a4l[ot][kc]);
        }
    half4 a5h[2], a5l[2];
    {
        int r5 = (l16 < 12) ? l16 : 11;        // clamp to avoid OOB, then zero
#pragma unroll
        for (int kc = 0; kc < 2; kc++) {
            f32x4 w = ld4(W5 + r5*32 + kc*16 + 4*qd);
            half4 h, l; split4(w, h, l);
            a5h[kc] = (l16 < 12) ? h : HZ;
            a5l[kc] = (l16 < 12) ? l : HZ;
        }
    }

    // ---------- MLP: 4 elem-tiles of 16, activations stay transposed in regs ----------
#pragma unroll 1
    for (int e = 0; e < 4; e++) {
        const int ce = wave_base + e*16 + l16;

        // Layer 1: G1 = relu(W1 x + b1), x in B-layout (k=4qd+j valid only qd==0)
        f32x4 xv = ld4(mc + (size_t)ce * 4);
        half4 bxh, bxl; split4(xv, bxh, bxl);
        bxh = (qd == 0) ? bxh : HZ;
        bxl = (qd == 0) ? bxl : HZ;
        f32x4 aH = ld4(b1 + 4*qd);
        f32x4 aL = FZ;
        aH = MFMA16(a1h, bxh, aH);
        aL = MFMA16(a1h, bxl, aL);
        aL = MFMA16(a1l, bxh, aL);
        f32x4 g1 = relu4(aH + aL * inv2048);
        half4 g1h, g1l; split4(g1, g1h, g1l);   // C-layout == next B-layout: no shuffle

        // Layer 2: 16 -> 32
        half4 g2h[2], g2l[2];
#pragma unroll
        for (int ot = 0; ot < 2; ot++) {
            f32x4 cH = ld4(b2 + ot*16 + 4*qd);
            f32x4 cL = FZ;
            cH = MFMA16(a2h[ot], g1h, cH);
            cL = MFMA16(a2h[ot], g1l, cL);
            cL = MFMA16(a2l[ot], g1h, cL);
            f32x4 g = relu4(cH + cL * inv2048);
            split4(g, g2h[ot], g2l[ot]);
        }

        // Layer 3: 32 -> 64
        half4 g3h[4], g3l[4];
#pragma unroll
        for (int ot = 0; ot < 4; ot++) {
            f32x4 cH = ld4(b3 + ot*16 + 4*qd);
            f32x4 cL = FZ;
#pragma unroll
            for (int kc = 0; kc < 2; kc++) {
                cH = MFMA16(a3h[ot][kc], g2h[kc], cH);
                cL = MFMA16(a3h[ot][kc], g2l[kc], cL);
                cL = MFMA16(a3l[ot][kc], g2h[kc], cL);
            }
            f32x4 g = relu4(cH + cL * inv2048);
            split4(g, g3h[ot], g3l[ot]);
        }

        // Layer 4: 64 -> 32
        half4 g4h[2], g4l[2];
#pragma unroll
        for (int ot = 0; ot < 2; ot++) {
            f32x4 cH = ld4(b4 + ot*16 + 4*qd);
            f32x4 cL = FZ;
#pragma unroll
            for (int kc = 0; kc < 4; kc++) {
                cH = MFMA16(a4h[ot][kc], g3h[kc], cH);
                cL = MFMA16(a4h[ot][kc], g3l[kc], cL);
                cL = MFMA16(a4l[ot][kc], g3h[kc], cL);
            }
            f32x4 g = relu4(cH + cL * inv2048);
            split4(g, g4h[ot], g4l[ot]);
        }

        // Layer 5: 32 -> 12 (rows 12-15 garbage, never read)
        {
            f32x4 cH = ld4(b5 + ((qd < 3) ? 4*qd : 8));
            cH = (qd < 3) ? cH : FZ;
            f32x4 cL = FZ;
#pragma unroll
            for (int kc = 0; kc < 2; kc++) {
                cH = MFMA16(a5h[kc], g4h[kc], cH);
                cL = MFMA16(a5h[kc], g4l[kc], cL);
                cL = MFMA16(a5l[kc], g4h[kc], cL);
            }
            f32x4 qv = relu4(cH + cL * inv2048);
            *(f32x4*)&qbuf[wv][(e*16 + l16)*20 + 4*qd] = qv;
        }
    }

    // all q writes are by this wave into its own region; drain LDS then read
    asm volatile("s_waitcnt lgkmcnt(0)" ::: "memory");

    float qq[12];
    {
        f32x4 qa = *(const f32x4*)&qbuf[wv][lane*20 + 0];
        f32x4 qb = *(const f32x4*)&qbuf[wv][lane*20 + 4];
        f32x4 qc = *(const f32x4*)&qbuf[wv][lane*20 + 8];
        qq[0] = qa[0]; qq[1] = qa[1]; qq[2]  = qa[2]; qq[3]  = qa[3];
        qq[4] = qb[0]; qq[5] = qb[1]; qq[6]  = qb[2]; qq[7]  = qb[3];
        qq[8] = qc[0]; qq[9] = qc[1]; qq[10] = qc[2]; qq[11] = qc[3];
    }

    // ---------- FK chain (fp32, verified round 1) ----------
    float M00 = 1.f, M01 = 0.f, M02 = 0.f;
    float M10 = 0.f, M11 = 1.f, M12 = 0.f;
    float M20 = 0.f, M21 = 0.f, M22 = 1.f;
    float v0 = 0.f, v1 = 0.f, v2 = 0.f;

#pragma unroll
    for (int j = 0; j < NJ; j++) {
        const float* c = jc + j*20;
        float wn = c[0];
        float u0 = c[1], u1 = c[2], u2 = c[3];
        float ru0 = c[4], ru1 = c[5], ru2 = c[6];
        float kru0 = c[7], kru1 = c[8], kru2 = c[9];
        float k2ru0 = c[10], k2ru1 = c[11], k2ru2 = c[12];
        float uu00 = c[13], uu01 = c[14], uu02 = c[15];
        float uu11 = c[16], uu12 = c[17], uu22 = c[18];

        float th = qq[j] * wn;
        float s = __sinf(th);
        float cth = __cosf(th);
        float cc = 1.0f - cth;
        float t = th - s;

        float R00 = 1.0f + cc*(uu00 - 1.0f);
        float R01 = cc*uu01 - s*u2;
        float R02 = cc*uu02 + s*u1;
        float R10 = cc*uu01 + s*u2;
        float R11 = 1.0f + cc*(uu11 - 1.0f);
        float R12 = cc*uu12 - s*u0;
        float R20 = cc*uu02 - s*u1;
        float R21 = cc*uu12 + s*u0;
        float R22 = 1.0f + cc*(uu22 - 1.0f);

        float p0 = th*ru0 + cc*kru0 + t*k2ru0;
        float p1 = th*ru1 + cc*kru1 + t*k2ru1;
        float p2 = th*ru2 + cc*kru2 + t*k2ru2;

        float n00 = M00*R00 + M01*R10 + M02*R20;
        float n01 = M00*R01 + M01*R11 + M02*R21;
        float n02 = M00*R02 + M01*R12 + M02*R22;
        float n10 = M10*R00 + M11*R10 + M12*R20;
        float n11 = M10*R01 + M11*R11 + M12*R21;
        float n12 = M10*R02 + M11*R12 + M12*R22;
        float n20 = M20*R00 + M21*R10 + M22*R20;
        float n21 = M20*R01 + M21*R11 + M22*R21;
        float n22 = M20*R02 + M21*R12 + M22*R22;
        v0 += M00*p0 + M01*p1 + M02*p2;
        v1 += M10*p0 + M11*p1 + M12*p2;
        v2 += M20*p0 + M21*p1 + M22*p2;
        M00 = n00; M01 = n01; M02 = n02;
        M10 = n10; M11 = n11; M12 = n12;
        M20 = n20; M21 = n21; M22 = n22;
    }

    const float* t0 = jc + NJ*20;
    float A00 = t0[0], A01 = t0[1], A02 = t0[2];
    float A10 = t0[3], A11 = t0[4], A12 = t0[5];
    float A20 = t0[6], A21 = t0[7], A22 = t0[8];
    float P0  = t0[9], P1  = t0[10], P2 = t0[11];

    float F00 = M00*A00 + M01*A10 + M02*A20;
    float F01 = M00*A01 + M01*A11 + M02*A21;
    float F02 = M00*A02 + M01*A12 + M02*A22;
    float F10 = M10*A00 + M11*A10 + M12*A20;
    float F11 = M10*A01 + M11*A11 + M12*A21;
    float F12 = M10*A02 + M11*A12 + M12*A22;
    float F20 = M20*A00 + M21*A10 + M22*A20;
    float F21 = M20*A01 + M21*A11 + M22*A21;
    float F22 = M20*A02 + M21*A12 + M22*A22;
    float Fv0 = M00*P0 + M01*P1 + M02*P2 + v0;
    float Fv1 = M10*P0 + M11*P1 + M12*P2 + v1;
    float Fv2 = M20*P0 + M21*P1 + M22*P2 + v2;

    const int eo = wave_base + lane;
    float4* o4 = (float4*)(out + (size_t)eo * 16);
    o4[0] = make_float4(F00, F01, F02, Fv0);
    o4[1] = make_float4(F10, F11, F12, Fv1);
    o4[2] = make_float4(F20, F21, F22, Fv2);
    o4[3] = make_float4(0.f, 0.f, 0.f, 1.f);
}

extern "C" void kernel_launch(void* const* d_in, const int* in_sizes, int n_in,
                              void* d_out, int out_size, void* d_ws, size_t ws_size,
                              hipStream_t stream) {
    const float* mc      = (const float*)d_in[0];
    const float* W1      = (const float*)d_in[1];
    const float* b1      = (const float*)d_in[2];
    const float* W2      = (const float*)d_in[3];
    const float* b2      = (const float*)d_in[4];
    const float* W3      = (const float*)d_in[5];
    const float* b3      = (const float*)d_in[6];
    const float* W4      = (const float*)d_in[7];
    const float* b4      = (const float*)d_in[8];
    const float* W5      = (const float*)d_in[9];
    const float* b5      = (const float*)d_in[10];
    const float* twist   = (const float*)d_in[11];
    const float* init_p  = (const float*)d_in[12];
    const float* init_rpy= (const float*)d_in[13];
    float* out = (float*)d_out;
    float* ws  = (float*)d_ws;

    precompute_kernel<<<1, 64, 0, stream>>>(twist, init_p, init_rpy, ws);
    fk_kernel<<<BATCH / 256, 256, 0, stream>>>(
        mc, W1, b1, W2, b2, W3, b3, W4, b4, W5, b5, ws, out);
}